// Round 1
// baseline (1829.550 us; speedup 1.0000x reference)
//
#include <hip/hip_runtime.h>
#include <hip/hip_bf16.h>
#include <math.h>

// GraphEncoderStack: 2x (GCNConv -> BN -> ReLU) + residual + 2 GCN heads + reparam
// N=50000 nodes, E=800000 edges, IN=HIDDEN=128, LATENT=32, fp32 throughout.

#define HID 128
#define LAT 32

// ---------------- degree / CSR construction ----------------

__global__ __launch_bounds__(256) void k_deg_init(float* deg, int n) {
  int i = blockIdx.x * 256 + threadIdx.x;
  if (i < n) deg[i] = 1.0f;  // self-loop weight 1
}

__global__ __launch_bounds__(256) void k_deg_edges(const int* __restrict__ dst,
    const float* __restrict__ w, float* deg, int* cnt, int E) {
  int e = blockIdx.x * 256 + threadIdx.x;
  if (e < E) {
    int d = dst[e];
    atomicAdd(&deg[d], w[e]);
    atomicAdd(&cnt[d], 1);
  }
}

__global__ __launch_bounds__(256) void k_dinv(float* deg, int n) {
  int i = blockIdx.x * 256 + threadIdx.x;
  if (i < n) { float d = deg[i]; deg[i] = d > 0.f ? rsqrtf(d) : 0.f; }
}

// single-block exclusive scan of cnt[n] -> off[n+1], pos=off copy
__global__ __launch_bounds__(1024) void k_scan(const int* __restrict__ cnt,
    int* __restrict__ off, int* __restrict__ pos, int n) {
  __shared__ int partial[1024];
  int t = threadIdx.x;
  int C = (n + 1023) >> 10;
  int b = t * C, e = min(b + C, n);
  int s = 0;
  for (int i = b; i < e; ++i) s += cnt[i];
  partial[t] = s;
  __syncthreads();
  for (int d = 1; d < 1024; d <<= 1) {
    int v = (t >= d) ? partial[t - d] : 0;
    __syncthreads();
    partial[t] += v;
    __syncthreads();
  }
  int run = (t == 0) ? 0 : partial[t - 1];
  for (int i = b; i < e; ++i) { off[i] = run; pos[i] = run; run += cnt[i]; }
  if (t == 1023) off[n] = partial[1023];
}

__global__ __launch_bounds__(256) void k_fill(const int* __restrict__ src,
    const int* __restrict__ dst, const float* __restrict__ w,
    const float* __restrict__ dinv, int* __restrict__ pos,
    int* __restrict__ csrc, float* __restrict__ cnorm, int E) {
  int e = blockIdx.x * 256 + threadIdx.x;
  if (e < E) {
    int s = src[e], d = dst[e];
    int p = atomicAdd(&pos[d], 1);
    csrc[p] = s;
    cnorm[p] = dinv[s] * w[e] * dinv[d];
  }
}

// ---------------- fp32 GEMM, K=128, NOUT in {128, 64} ----------------
// W columns cached in VGPRs (float2), x tile staged in LDS (broadcast reads).

#define TM 32
template <int NOUT>
__global__ __launch_bounds__(256) void k_gemm(const float* __restrict__ X,
    const float* __restrict__ W, float* __restrict__ Y, int n) {
  constexpr int NCOLT = NOUT / 2;      // thread-cols (2 cols each)
  constexpr int NRG = 256 / NCOLT;     // row groups
  constexpr int RPT = TM / NRG;        // rows per thread
  __shared__ float xs[TM * 128];
  const int t = threadIdx.x;
  const int cc = t % NCOLT;
  const int rg = t / NCOLT;
  const int c = cc * 2;
  const int row0 = blockIdx.x * TM;
  for (int i = t; i < TM * 32; i += 256) {
    int r = i / 32;
    float4 v = (row0 + r < n)
        ? ((const float4*)X)[(size_t)(row0 + r) * 32 + (i % 32)]
        : make_float4(0.f, 0.f, 0.f, 0.f);
    ((float4*)xs)[i] = v;
  }
  __syncthreads();
  float acc[RPT][2];
#pragma unroll
  for (int i = 0; i < RPT; ++i) { acc[i][0] = 0.f; acc[i][1] = 0.f; }
#pragma unroll
  for (int chunk = 0; chunk < 2; ++chunk) {
    float2 w[64];
#pragma unroll
    for (int kk = 0; kk < 64; ++kk)
      w[kk] = *(const float2*)&W[(size_t)(chunk * 64 + kk) * NOUT + c];
#pragma unroll
    for (int ri = 0; ri < RPT; ++ri) {
      const int rl = rg + ri * NRG;
      const float4* xr = (const float4*)&xs[rl * 128 + chunk * 64];
      float a0 = acc[ri][0], a1 = acc[ri][1];
#pragma unroll
      for (int k4 = 0; k4 < 16; ++k4) {
        float4 xv = xr[k4];
        a0 = fmaf(xv.x, w[k4 * 4 + 0].x, a0); a1 = fmaf(xv.x, w[k4 * 4 + 0].y, a1);
        a0 = fmaf(xv.y, w[k4 * 4 + 1].x, a0); a1 = fmaf(xv.y, w[k4 * 4 + 1].y, a1);
        a0 = fmaf(xv.z, w[k4 * 4 + 2].x, a0); a1 = fmaf(xv.z, w[k4 * 4 + 2].y, a1);
        a0 = fmaf(xv.w, w[k4 * 4 + 3].x, a0); a1 = fmaf(xv.w, w[k4 * 4 + 3].y, a1);
      }
      acc[ri][0] = a0; acc[ri][1] = a1;
    }
  }
#pragma unroll
  for (int ri = 0; ri < RPT; ++ri) {
    int r = row0 + rg + ri * NRG;
    if (r < n) {
      Y[(size_t)r * NOUT + c] = acc[ri][0];
      Y[(size_t)r * NOUT + c + 1] = acc[ri][1];
    }
  }
}

// ---------------- CSR propagation: out[d] = sum norm*T[src] + self + bias ----
template <int F>
__global__ __launch_bounds__(256) void k_prop(const float* __restrict__ T,
    const float* __restrict__ dinv, const int* __restrict__ off,
    const int* __restrict__ csrc, const float* __restrict__ cnorm,
    const float* __restrict__ bias, float* __restrict__ out, int n) {
  constexpr int NPB = 256 / F;
  int node = blockIdx.x * NPB + threadIdx.x / F;
  int f = threadIdx.x % F;
  if (node >= n) return;
  float di = dinv[node];
  float acc = di * di * T[(size_t)node * F + f];
  int e = off[node], eend = off[node + 1];
  for (; e + 1 < eend; e += 2) {
    int s0 = csrc[e], s1 = csrc[e + 1];
    float n0 = cnorm[e], n1 = cnorm[e + 1];
    acc += n0 * T[(size_t)s0 * F + f];
    acc += n1 * T[(size_t)s1 * F + f];
  }
  if (e < eend) acc += cnorm[e] * T[(size_t)csrc[e] * F + f];
  out[(size_t)node * F + f] = acc + bias[f];
}

// ---------------- BatchNorm ----------------

__global__ __launch_bounds__(128) void k_stats(const float* __restrict__ X,
    float* __restrict__ stats, int n) {
  int col = threadIdx.x;
  float s = 0.f, s2 = 0.f;
  for (int r = blockIdx.x; r < n; r += gridDim.x) {
    float v = X[(size_t)r * 128 + col];
    s += v; s2 += v * v;
  }
  atomicAdd(&stats[col], s);
  atomicAdd(&stats[128 + col], s2);
}

__global__ __launch_bounds__(128) void k_bnfin(const float* __restrict__ stats,
    const float* __restrict__ g, const float* __restrict__ be,
    float* __restrict__ scsh, int n) {
  int c = threadIdx.x;
  float m = stats[c] / (float)n;
  float var = stats[128 + c] / (float)n - m * m;
  var = fmaxf(var, 0.f);
  float sc = g[c] * rsqrtf(var + 1e-5f);
  scsh[c] = sc;
  scsh[128 + c] = be[c] - m * sc;
}

template <int ADDRES>
__global__ __launch_bounds__(256) void k_bnact(const float4* __restrict__ in4,
    const float* __restrict__ scsh, const float4* __restrict__ res4,
    float4* __restrict__ out4, int n4) {
  int i = blockIdx.x * 256 + threadIdx.x;
  if (i >= n4) return;
  int c4 = (i & 31) * 4;
  float4 v = in4[i];
  float4 r;
  r.x = fmaxf(v.x * scsh[c4 + 0] + scsh[128 + c4 + 0], 0.f);
  r.y = fmaxf(v.y * scsh[c4 + 1] + scsh[128 + c4 + 1], 0.f);
  r.z = fmaxf(v.z * scsh[c4 + 2] + scsh[128 + c4 + 2], 0.f);
  r.w = fmaxf(v.w * scsh[c4 + 3] + scsh[128 + c4 + 3], 0.f);
  if (ADDRES) {
    float4 q = res4[i];
    r.x += q.x; r.y += q.y; r.z += q.z; r.w += q.w;
  }
  out4[i] = r;
}

// ---------------- head weight concat + final reparam ----------------

__global__ __launch_bounds__(256) void k_concat(const float* __restrict__ Wm,
    const float* __restrict__ bm, const float* __restrict__ Ws,
    const float* __restrict__ bs, float* __restrict__ wcat,
    float* __restrict__ bcat) {
  int t = blockIdx.x * 256 + threadIdx.x;
  if (t < 128 * 64) {
    int k = t / 64, c = t % 64;
    wcat[t] = (c < 32) ? Wm[k * 32 + c] : Ws[k * 32 + (c - 32)];
  } else if (t < 128 * 64 + 64) {
    int c = t - 128 * 64;
    bcat[c] = (c < 32) ? bm[c] : bs[c - 32];
  }
}

__global__ __launch_bounds__(256) void k_final(const float* __restrict__ agg,
    const float* __restrict__ eps, float* __restrict__ out, int n) {
  int i = blockIdx.x * 256 + threadIdx.x;
  int M = n * 32;
  if (i >= M) return;
  int node = i >> 5, j = i & 31;
  float qm = agg[(size_t)node * 64 + j];
  float qs = agg[(size_t)node * 64 + 32 + j];
  float sp = fmaxf(qs, 0.f) + log1pf(expf(-fabsf(qs)));
  float stdv = sp + 1e-6f;
  out[i] = qm + stdv * eps[i];
  out[M + i] = qm;
  out[2 * M + i] = qs;
}

// ---------------- launch ----------------

extern "C" void kernel_launch(void* const* d_in, const int* in_sizes, int n_in,
                              void* d_out, int out_size, void* d_ws, size_t ws_size,
                              hipStream_t stream) {
  const float* x  = (const float*)d_in[0];
  const int*   ei = (const int*)d_in[1];
  const float* ew = (const float*)d_in[2];
  const float* W0 = (const float*)d_in[3];
  const float* b0 = (const float*)d_in[4];
  const float* W1 = (const float*)d_in[5];
  const float* b1 = (const float*)d_in[6];
  const float* g0 = (const float*)d_in[7];
  const float* be0 = (const float*)d_in[8];
  const float* g1 = (const float*)d_in[9];
  const float* be1 = (const float*)d_in[10];
  const float* Wm = (const float*)d_in[11];
  const float* bm = (const float*)d_in[12];
  const float* Ws = (const float*)d_in[13];
  const float* bs = (const float*)d_in[14];
  const float* eps = (const float*)d_in[15];
  float* out = (float*)d_out;

  const int n = in_sizes[0] / HID;
  const int E = in_sizes[1] / 2;
  const int* esrc = ei;
  const int* edst = ei + E;

  // workspace layout (256B aligned)
  char* base = (char*)d_ws;
  size_t cur = 0;
  auto alloc = [&](size_t bytes) {
    size_t o = cur;
    cur = (cur + bytes + 255) & ~(size_t)255;
    return (void*)(base + o);
  };
  float* deg   = (float*)alloc((size_t)n * 4);        // becomes dinv
  int*   cnt   = (int*)alloc((size_t)n * 4);
  int*   coff  = (int*)alloc((size_t)(n + 1) * 4);
  int*   cpos  = (int*)alloc((size_t)n * 4);
  int*   csrc  = (int*)alloc((size_t)E * 4);
  float* cnorm = (float*)alloc((size_t)E * 4);
  float* stats = (float*)alloc(256 * 4);
  float* scsh  = (float*)alloc(256 * 4);
  float* wcat  = (float*)alloc(128 * 64 * 4);
  float* bcat  = (float*)alloc(64 * 4);
  float* bufA  = (float*)alloc((size_t)n * 128 * 4);
  float* bufB  = (float*)alloc((size_t)n * 128 * 4);
  float* bufC  = (float*)alloc((size_t)n * 128 * 4);
  (void)ws_size;

  const int nb = (n + 255) / 256;
  const int eb = (E + 255) / 256;
  const int gemmb = (n + TM - 1) / TM;
  const int n4 = n * 32;          // float4 count for [n,128]
  const int n4b = (n4 + 255) / 256;
  const int mlat = n * 32;        // latent elements
  const int mlatb = (mlat + 255) / 256;

  // --- norm + CSR ---
  hipMemsetAsync(cnt, 0, (size_t)n * 4, stream);
  k_deg_init<<<nb, 256, 0, stream>>>(deg, n);
  k_deg_edges<<<eb, 256, 0, stream>>>(edst, ew, deg, cnt, E);
  k_dinv<<<nb, 256, 0, stream>>>(deg, n);
  k_scan<<<1, 1024, 0, stream>>>(cnt, coff, cpos, n);
  k_fill<<<eb, 256, 0, stream>>>(esrc, edst, ew, deg, cpos, csrc, cnorm, E);
  k_concat<<<(128 * 64 + 64 + 255) / 256, 256, 0, stream>>>(Wm, bm, Ws, bs, wcat, bcat);

  // --- layer 0 ---
  k_gemm<128><<<gemmb, 256, 0, stream>>>(x, W0, bufA, n);
  k_prop<128><<<(n + 1) / 2, 256, 0, stream>>>(bufA, deg, coff, csrc, cnorm, b0, bufB, n);
  hipMemsetAsync(stats, 0, 256 * 4, stream);
  k_stats<<<512, 128, 0, stream>>>(bufB, stats, n);
  k_bnfin<<<1, 128, 0, stream>>>(stats, g0, be0, scsh, n);
  k_bnact<0><<<n4b, 256, 0, stream>>>((const float4*)bufB, scsh, nullptr,
                                      (float4*)bufC, n4);  // bufC = h0 (residual)

  // --- layer 1 ---
  k_gemm<128><<<gemmb, 256, 0, stream>>>(bufC, W1, bufA, n);
  k_prop<128><<<(n + 1) / 2, 256, 0, stream>>>(bufA, deg, coff, csrc, cnorm, b1, bufB, n);
  hipMemsetAsync(stats, 0, 256 * 4, stream);
  k_stats<<<512, 128, 0, stream>>>(bufB, stats, n);
  k_bnfin<<<1, 128, 0, stream>>>(stats, g1, be1, scsh, n);
  k_bnact<1><<<n4b, 256, 0, stream>>>((const float4*)bufB, scsh, (const float4*)bufC,
                                      (float4*)bufA, n4);  // bufA = h

  // --- heads (fused mean||logstd, width 64) ---
  k_gemm<64><<<gemmb, 256, 0, stream>>>(bufA, wcat, bufB, n);
  k_prop<64><<<(n + 3) / 4, 256, 0, stream>>>(bufB, deg, coff, csrc, cnorm, bcat, bufC, n);

  // --- reparameterization + output ---
  k_final<<<mlatb, 256, 0, stream>>>(bufC, eps, out, n);
}

// Round 2
// 626.255 us; speedup vs baseline: 2.9214x; 2.9214x over previous
//
#include <hip/hip_runtime.h>
#include <hip/hip_bf16.h>
#include <math.h>

// GraphEncoderStack: 2x (GCNConv -> BN -> ReLU) + residual + 2 GCN heads + reparam
// N=50000 nodes, E=800000 edges, IN=HIDDEN=128, LATENT=32, fp32 throughout.

#define HID 128
#define LAT 32

// ---------------- degree / CSR construction ----------------

__global__ __launch_bounds__(256) void k_deg_init(float* deg, int n) {
  int i = blockIdx.x * 256 + threadIdx.x;
  if (i < n) deg[i] = 1.0f;  // self-loop weight 1
}

__global__ __launch_bounds__(256) void k_deg_edges(const int* __restrict__ dst,
    const float* __restrict__ w, float* deg, int* cnt, int E) {
  int e = blockIdx.x * 256 + threadIdx.x;
  if (e < E) {
    int d = dst[e];
    atomicAdd(&deg[d], w[e]);
    atomicAdd(&cnt[d], 1);
  }
}

__global__ __launch_bounds__(256) void k_dinv(float* deg, int n) {
  int i = blockIdx.x * 256 + threadIdx.x;
  if (i < n) { float d = deg[i]; deg[i] = d > 0.f ? rsqrtf(d) : 0.f; }
}

// single-block exclusive scan of cnt[n] -> off[n+1], pos=off copy
__global__ __launch_bounds__(1024) void k_scan(const int* __restrict__ cnt,
    int* __restrict__ off, int* __restrict__ pos, int n) {
  __shared__ int partial[1024];
  int t = threadIdx.x;
  int C = (n + 1023) >> 10;
  int b = t * C, e = min(b + C, n);
  int s = 0;
  for (int i = b; i < e; ++i) s += cnt[i];
  partial[t] = s;
  __syncthreads();
  for (int d = 1; d < 1024; d <<= 1) {
    int v = (t >= d) ? partial[t - d] : 0;
    __syncthreads();
    partial[t] += v;
    __syncthreads();
  }
  int run = (t == 0) ? 0 : partial[t - 1];
  for (int i = b; i < e; ++i) { off[i] = run; pos[i] = run; run += cnt[i]; }
  if (t == 1023) off[n] = partial[1023];
}

__global__ __launch_bounds__(256) void k_fill(const int* __restrict__ src,
    const int* __restrict__ dst, const float* __restrict__ w,
    const float* __restrict__ dinv, int* __restrict__ pos,
    int* __restrict__ csrc, float* __restrict__ cnorm, int E) {
  int e = blockIdx.x * 256 + threadIdx.x;
  if (e < E) {
    int s = src[e], d = dst[e];
    int p = atomicAdd(&pos[d], 1);
    csrc[p] = s;
    cnorm[p] = dinv[s] * w[e] * dinv[d];
  }
}

// ---------------- fp32 GEMM, K=128, NOUT in {128, 64} ----------------
// 64-row tile staged in LDS (padded stride); each thread: 8 cols x RPT rows.
// W read from global (L1/L2 broadcast). ~100 VGPRs -> no spill.

#define TMG 64
template <int NOUT>
__global__ __launch_bounds__(256) void k_gemm(const float* __restrict__ X,
    const float* __restrict__ W, float* __restrict__ Y, int n) {
  constexpr int NCT = NOUT / 8;        // threads covering cols (8 cols each)
  constexpr int NRG = 256 / NCT;       // row groups
  constexpr int RPT = TMG / NRG;       // rows per thread
  constexpr int LDSTR = 132;           // padded row stride (floats), 16B-aligned
  __shared__ float xs[TMG * LDSTR];
  const int t = threadIdx.x;
  const int ct = t % NCT;
  const int rg = t / NCT;
  const int c = ct * 8;
  const int row0 = blockIdx.x * TMG;
  for (int i = t; i < TMG * 32; i += 256) {
    int r = i >> 5, q = i & 31;
    float4 v = (row0 + r < n)
        ? ((const float4*)X)[(size_t)(row0 + r) * 32 + q]
        : make_float4(0.f, 0.f, 0.f, 0.f);
    *(float4*)&xs[r * LDSTR + q * 4] = v;
  }
  __syncthreads();
  float acc[RPT][8];
#pragma unroll
  for (int i = 0; i < RPT; ++i)
#pragma unroll
    for (int j = 0; j < 8; ++j) acc[i][j] = 0.f;

#pragma unroll 4
  for (int k = 0; k < 128; k += 4) {
    float4 wa[4], wb[4];
#pragma unroll
    for (int kk = 0; kk < 4; ++kk) {
      wa[kk] = *(const float4*)&W[(size_t)(k + kk) * NOUT + c];
      wb[kk] = *(const float4*)&W[(size_t)(k + kk) * NOUT + c + 4];
    }
#pragma unroll
    for (int ri = 0; ri < RPT; ++ri) {
      const int rl = rg * RPT + ri;
      float4 xv = *(const float4*)&xs[rl * LDSTR + k];
      acc[ri][0] = fmaf(xv.x, wa[0].x, acc[ri][0]);
      acc[ri][1] = fmaf(xv.x, wa[0].y, acc[ri][1]);
      acc[ri][2] = fmaf(xv.x, wa[0].z, acc[ri][2]);
      acc[ri][3] = fmaf(xv.x, wa[0].w, acc[ri][3]);
      acc[ri][4] = fmaf(xv.x, wb[0].x, acc[ri][4]);
      acc[ri][5] = fmaf(xv.x, wb[0].y, acc[ri][5]);
      acc[ri][6] = fmaf(xv.x, wb[0].z, acc[ri][6]);
      acc[ri][7] = fmaf(xv.x, wb[0].w, acc[ri][7]);
      acc[ri][0] = fmaf(xv.y, wa[1].x, acc[ri][0]);
      acc[ri][1] = fmaf(xv.y, wa[1].y, acc[ri][1]);
      acc[ri][2] = fmaf(xv.y, wa[1].z, acc[ri][2]);
      acc[ri][3] = fmaf(xv.y, wa[1].w, acc[ri][3]);
      acc[ri][4] = fmaf(xv.y, wb[1].x, acc[ri][4]);
      acc[ri][5] = fmaf(xv.y, wb[1].y, acc[ri][5]);
      acc[ri][6] = fmaf(xv.y, wb[1].z, acc[ri][6]);
      acc[ri][7] = fmaf(xv.y, wb[1].w, acc[ri][7]);
      acc[ri][0] = fmaf(xv.z, wa[2].x, acc[ri][0]);
      acc[ri][1] = fmaf(xv.z, wa[2].y, acc[ri][1]);
      acc[ri][2] = fmaf(xv.z, wa[2].z, acc[ri][2]);
      acc[ri][3] = fmaf(xv.z, wa[2].w, acc[ri][3]);
      acc[ri][4] = fmaf(xv.z, wb[2].x, acc[ri][4]);
      acc[ri][5] = fmaf(xv.z, wb[2].y, acc[ri][5]);
      acc[ri][6] = fmaf(xv.z, wb[2].z, acc[ri][6]);
      acc[ri][7] = fmaf(xv.z, wb[2].w, acc[ri][7]);
      acc[ri][0] = fmaf(xv.w, wa[3].x, acc[ri][0]);
      acc[ri][1] = fmaf(xv.w, wa[3].y, acc[ri][1]);
      acc[ri][2] = fmaf(xv.w, wa[3].z, acc[ri][2]);
      acc[ri][3] = fmaf(xv.w, wa[3].w, acc[ri][3]);
      acc[ri][4] = fmaf(xv.w, wb[3].x, acc[ri][4]);
      acc[ri][5] = fmaf(xv.w, wb[3].y, acc[ri][5]);
      acc[ri][6] = fmaf(xv.w, wb[3].z, acc[ri][6]);
      acc[ri][7] = fmaf(xv.w, wb[3].w, acc[ri][7]);
    }
  }
#pragma unroll
  for (int ri = 0; ri < RPT; ++ri) {
    int r = row0 + rg * RPT + ri;
    if (r < n) {
      *(float4*)&Y[(size_t)r * NOUT + c] =
          make_float4(acc[ri][0], acc[ri][1], acc[ri][2], acc[ri][3]);
      *(float4*)&Y[(size_t)r * NOUT + c + 4] =
          make_float4(acc[ri][4], acc[ri][5], acc[ri][6], acc[ri][7]);
    }
  }
}

// ---------------- CSR propagation: out[d] = sum norm*T[src] + self + bias ----
// float4 lanes: F/4 threads per node.
template <int F>
__global__ __launch_bounds__(256) void k_prop4(const float* __restrict__ T,
    const float* __restrict__ dinv, const int* __restrict__ off,
    const int* __restrict__ csrc, const float* __restrict__ cnorm,
    const float* __restrict__ bias, float* __restrict__ out, int n) {
  constexpr int TPN = F / 4;
  constexpr int NPB = 256 / TPN;
  int node = blockIdx.x * NPB + threadIdx.x / TPN;
  int f4 = threadIdx.x % TPN;
  if (node >= n) return;
  const float4* T4 = (const float4*)T;
  float di = dinv[node];
  float sw = di * di;
  float4 x = T4[(size_t)node * TPN + f4];
  float4 acc = make_float4(sw * x.x, sw * x.y, sw * x.z, sw * x.w);
  int e = off[node], eend = off[node + 1];
  for (; e + 1 < eend; e += 2) {
    int s0 = csrc[e], s1 = csrc[e + 1];
    float n0 = cnorm[e], n1 = cnorm[e + 1];
    float4 v0 = T4[(size_t)s0 * TPN + f4];
    float4 v1 = T4[(size_t)s1 * TPN + f4];
    acc.x = fmaf(n0, v0.x, acc.x); acc.y = fmaf(n0, v0.y, acc.y);
    acc.z = fmaf(n0, v0.z, acc.z); acc.w = fmaf(n0, v0.w, acc.w);
    acc.x = fmaf(n1, v1.x, acc.x); acc.y = fmaf(n1, v1.y, acc.y);
    acc.z = fmaf(n1, v1.z, acc.z); acc.w = fmaf(n1, v1.w, acc.w);
  }
  if (e < eend) {
    float nw = cnorm[e];
    float4 v = T4[(size_t)csrc[e] * TPN + f4];
    acc.x = fmaf(nw, v.x, acc.x); acc.y = fmaf(nw, v.y, acc.y);
    acc.z = fmaf(nw, v.z, acc.z); acc.w = fmaf(nw, v.w, acc.w);
  }
  float4 b = *(const float4*)&bias[f4 * 4];
  acc.x += b.x; acc.y += b.y; acc.z += b.z; acc.w += b.w;
  ((float4*)out)[(size_t)node * TPN + f4] = acc;
}

// ---------------- BatchNorm ----------------

__global__ __launch_bounds__(128) void k_stats(const float* __restrict__ X,
    float* __restrict__ stats, int n) {
  int col = threadIdx.x;
  float s = 0.f, s2 = 0.f;
  for (int r = blockIdx.x; r < n; r += gridDim.x) {
    float v = X[(size_t)r * 128 + col];
    s += v; s2 += v * v;
  }
  atomicAdd(&stats[col], s);
  atomicAdd(&stats[128 + col], s2);
}

__global__ __launch_bounds__(128) void k_bnfin(const float* __restrict__ stats,
    const float* __restrict__ g, const float* __restrict__ be,
    float* __restrict__ scsh, int n) {
  int c = threadIdx.x;
  float m = stats[c] / (float)n;
  float var = stats[128 + c] / (float)n - m * m;
  var = fmaxf(var, 0.f);
  float sc = g[c] * rsqrtf(var + 1e-5f);
  scsh[c] = sc;
  scsh[128 + c] = be[c] - m * sc;
}

template <int ADDRES>
__global__ __launch_bounds__(256) void k_bnact(const float4* __restrict__ in4,
    const float* __restrict__ scsh, const float4* __restrict__ res4,
    float4* __restrict__ out4, int n4) {
  int i = blockIdx.x * 256 + threadIdx.x;
  if (i >= n4) return;
  int c4 = (i & 31) * 4;
  float4 v = in4[i];
  float4 r;
  r.x = fmaxf(v.x * scsh[c4 + 0] + scsh[128 + c4 + 0], 0.f);
  r.y = fmaxf(v.y * scsh[c4 + 1] + scsh[128 + c4 + 1], 0.f);
  r.z = fmaxf(v.z * scsh[c4 + 2] + scsh[128 + c4 + 2], 0.f);
  r.w = fmaxf(v.w * scsh[c4 + 3] + scsh[128 + c4 + 3], 0.f);
  if (ADDRES) {
    float4 q = res4[i];
    r.x += q.x; r.y += q.y; r.z += q.z; r.w += q.w;
  }
  out4[i] = r;
}

// ---------------- head weight concat + final reparam ----------------

__global__ __launch_bounds__(256) void k_concat(const float* __restrict__ Wm,
    const float* __restrict__ bm, const float* __restrict__ Ws,
    const float* __restrict__ bs, float* __restrict__ wcat,
    float* __restrict__ bcat) {
  int t = blockIdx.x * 256 + threadIdx.x;
  if (t < 128 * 64) {
    int k = t / 64, c = t % 64;
    wcat[t] = (c < 32) ? Wm[k * 32 + c] : Ws[k * 32 + (c - 32)];
  } else if (t < 128 * 64 + 64) {
    int c = t - 128 * 64;
    bcat[c] = (c < 32) ? bm[c] : bs[c - 32];
  }
}

__global__ __launch_bounds__(256) void k_final(const float* __restrict__ agg,
    const float* __restrict__ eps, float* __restrict__ out, int n) {
  int i = blockIdx.x * 256 + threadIdx.x;
  int M = n * 32;
  if (i >= M) return;
  int node = i >> 5, j = i & 31;
  float qm = agg[(size_t)node * 64 + j];
  float qs = agg[(size_t)node * 64 + 32 + j];
  float sp = fmaxf(qs, 0.f) + log1pf(expf(-fabsf(qs)));
  float stdv = sp + 1e-6f;
  out[i] = qm + stdv * eps[i];
  out[M + i] = qm;
  out[2 * M + i] = qs;
}

// ---------------- launch ----------------

extern "C" void kernel_launch(void* const* d_in, const int* in_sizes, int n_in,
                              void* d_out, int out_size, void* d_ws, size_t ws_size,
                              hipStream_t stream) {
  const float* x  = (const float*)d_in[0];
  const int*   ei = (const int*)d_in[1];
  const float* ew = (const float*)d_in[2];
  const float* W0 = (const float*)d_in[3];
  const float* b0 = (const float*)d_in[4];
  const float* W1 = (const float*)d_in[5];
  const float* b1 = (const float*)d_in[6];
  const float* g0 = (const float*)d_in[7];
  const float* be0 = (const float*)d_in[8];
  const float* g1 = (const float*)d_in[9];
  const float* be1 = (const float*)d_in[10];
  const float* Wm = (const float*)d_in[11];
  const float* bm = (const float*)d_in[12];
  const float* Ws = (const float*)d_in[13];
  const float* bs = (const float*)d_in[14];
  const float* eps = (const float*)d_in[15];
  float* out = (float*)d_out;

  const int n = in_sizes[0] / HID;
  const int E = in_sizes[1] / 2;
  const int* esrc = ei;
  const int* edst = ei + E;

  // workspace layout (256B aligned)
  char* base = (char*)d_ws;
  size_t cur = 0;
  auto alloc = [&](size_t bytes) {
    size_t o = cur;
    cur = (cur + bytes + 255) & ~(size_t)255;
    return (void*)(base + o);
  };
  float* deg   = (float*)alloc((size_t)n * 4);        // becomes dinv
  int*   cnt   = (int*)alloc((size_t)n * 4);
  int*   coff  = (int*)alloc((size_t)(n + 1) * 4);
  int*   cpos  = (int*)alloc((size_t)n * 4);
  int*   csrc  = (int*)alloc((size_t)E * 4);
  float* cnorm = (float*)alloc((size_t)E * 4);
  float* stats = (float*)alloc(256 * 4);
  float* scsh  = (float*)alloc(256 * 4);
  float* wcat  = (float*)alloc(128 * 64 * 4);
  float* bcat  = (float*)alloc(64 * 4);
  float* bufA  = (float*)alloc((size_t)n * 128 * 4);
  float* bufB  = (float*)alloc((size_t)n * 128 * 4);
  float* bufC  = (float*)alloc((size_t)n * 128 * 4);
  (void)ws_size;

  const int nb = (n + 255) / 256;
  const int eb = (E + 255) / 256;
  const int gemmb = (n + TMG - 1) / TMG;
  const int n4 = n * 32;          // float4 count for [n,128]
  const int n4b = (n4 + 255) / 256;
  const int mlat = n * 32;        // latent elements
  const int mlatb = (mlat + 255) / 256;

  // --- norm + CSR ---
  hipMemsetAsync(cnt, 0, (size_t)n * 4, stream);
  k_deg_init<<<nb, 256, 0, stream>>>(deg, n);
  k_deg_edges<<<eb, 256, 0, stream>>>(edst, ew, deg, cnt, E);
  k_dinv<<<nb, 256, 0, stream>>>(deg, n);
  k_scan<<<1, 1024, 0, stream>>>(cnt, coff, cpos, n);
  k_fill<<<eb, 256, 0, stream>>>(esrc, edst, ew, deg, cpos, csrc, cnorm, E);
  k_concat<<<(128 * 64 + 64 + 255) / 256, 256, 0, stream>>>(Wm, bm, Ws, bs, wcat, bcat);

  // --- layer 0 ---
  k_gemm<128><<<gemmb, 256, 0, stream>>>(x, W0, bufA, n);
  k_prop4<128><<<(n + 7) / 8, 256, 0, stream>>>(bufA, deg, coff, csrc, cnorm, b0, bufB, n);
  hipMemsetAsync(stats, 0, 256 * 4, stream);
  k_stats<<<512, 128, 0, stream>>>(bufB, stats, n);
  k_bnfin<<<1, 128, 0, stream>>>(stats, g0, be0, scsh, n);
  k_bnact<0><<<n4b, 256, 0, stream>>>((const float4*)bufB, scsh, nullptr,
                                      (float4*)bufC, n4);  // bufC = h0 (residual)

  // --- layer 1 ---
  k_gemm<128><<<gemmb, 256, 0, stream>>>(bufC, W1, bufA, n);
  k_prop4<128><<<(n + 7) / 8, 256, 0, stream>>>(bufA, deg, coff, csrc, cnorm, b1, bufB, n);
  hipMemsetAsync(stats, 0, 256 * 4, stream);
  k_stats<<<512, 128, 0, stream>>>(bufB, stats, n);
  k_bnfin<<<1, 128, 0, stream>>>(stats, g1, be1, scsh, n);
  k_bnact<1><<<n4b, 256, 0, stream>>>((const float4*)bufB, scsh, (const float4*)bufC,
                                      (float4*)bufA, n4);  // bufA = h

  // --- heads (fused mean||logstd, width 64) ---
  k_gemm<64><<<gemmb, 256, 0, stream>>>(bufA, wcat, bufB, n);
  k_prop4<64><<<(n + 15) / 16, 256, 0, stream>>>(bufB, deg, coff, csrc, cnorm, bcat, bufC, n);

  // --- reparameterization + output ---
  k_final<<<mlatb, 256, 0, stream>>>(bufC, eps, out, n);
}

// Round 3
// 512.261 us; speedup vs baseline: 3.5715x; 1.2225x over previous
//
#include <hip/hip_runtime.h>
#include <hip/hip_bf16.h>
#include <math.h>

// GraphEncoderStack: 2x (GCNConv -> BN -> ReLU) + residual + 2 GCN heads + reparam
// N=50000 nodes, E=800000 edges, IN=HIDDEN=128, LATENT=32, fp32 throughout.

#define HID 128
#define LAT 32

// ---------------- degree / CSR construction ----------------

__global__ __launch_bounds__(256) void k_deg_init(float* deg, int n) {
  int i = blockIdx.x * 256 + threadIdx.x;
  if (i < n) deg[i] = 1.0f;  // self-loop weight 1
}

__global__ __launch_bounds__(256) void k_deg_edges(const int* __restrict__ dst,
    const float* __restrict__ w, float* deg, int* cnt, int E) {
  int e = blockIdx.x * 256 + threadIdx.x;
  if (e < E) {
    int d = dst[e];
    atomicAdd(&deg[d], w[e]);
    atomicAdd(&cnt[d], 1);
  }
}

__global__ __launch_bounds__(256) void k_dinv(float* deg, int n) {
  int i = blockIdx.x * 256 + threadIdx.x;
  if (i < n) { float d = deg[i]; deg[i] = d > 0.f ? rsqrtf(d) : 0.f; }
}

// ---------------- hierarchical exclusive scan (n <= 65536) ----------------
// SCH=1024 elems/block; nb=ceil(n/1024)<=64 -> mid scan fits one wave.
#define SCH 1024

__global__ __launch_bounds__(256) void k_scan_part(const int* __restrict__ cnt,
    int* __restrict__ bsum, int n) {
  int base = blockIdx.x * SCH + threadIdx.x * 4;
  int4 v = make_int4(0, 0, 0, 0);
  if (base + 3 < n) v = *(const int4*)&cnt[base];
  else {
    if (base + 0 < n) v.x = cnt[base + 0];
    if (base + 1 < n) v.y = cnt[base + 1];
    if (base + 2 < n) v.z = cnt[base + 2];
  }
  int s = v.x + v.y + v.z + v.w;
#pragma unroll
  for (int off = 32; off; off >>= 1) s += __shfl_down(s, off);
  __shared__ int ws[4];
  if ((threadIdx.x & 63) == 0) ws[threadIdx.x >> 6] = s;
  __syncthreads();
  if (threadIdx.x == 0) bsum[blockIdx.x] = ws[0] + ws[1] + ws[2] + ws[3];
}

__global__ __launch_bounds__(64) void k_scan_mid(const int* __restrict__ bsum,
    int* __restrict__ boff, int* __restrict__ off, int nb, int n) {
  int t = threadIdx.x;
  int val = (t < nb) ? bsum[t] : 0;
  int inc = val;
#pragma unroll
  for (int d = 1; d < 64; d <<= 1) {
    int u = __shfl_up(inc, d);
    if (t >= d) inc += u;
  }
  if (t < nb) boff[t] = inc - val;
  if (t == nb - 1) off[n] = inc;  // grand total = E + n
}

__global__ __launch_bounds__(256) void k_scan_out(const int* __restrict__ cnt,
    const int* __restrict__ boff, int* __restrict__ off, int* __restrict__ pos,
    int n) {
  int base = blockIdx.x * SCH + threadIdx.x * 4;
  int4 v = make_int4(0, 0, 0, 0);
  if (base + 3 < n) v = *(const int4*)&cnt[base];
  else {
    if (base + 0 < n) v.x = cnt[base + 0];
    if (base + 1 < n) v.y = cnt[base + 1];
    if (base + 2 < n) v.z = cnt[base + 2];
  }
  int s = v.x + v.y + v.z + v.w;
  int lane = threadIdx.x & 63, wv = threadIdx.x >> 6;
  int inc = s;
#pragma unroll
  for (int d = 1; d < 64; d <<= 1) {
    int u = __shfl_up(inc, d);
    if (lane >= d) inc += u;
  }
  __shared__ int wsum[4];
  if (lane == 63) wsum[wv] = inc;
  __syncthreads();
  int wbase = 0;
  for (int i = 0; i < wv; ++i) wbase += wsum[i];
  int ex = boff[blockIdx.x] + wbase + inc - s;
  int4 o = make_int4(ex, ex + v.x, ex + v.x + v.y, ex + v.x + v.y + v.z);
  if (base + 3 < n) {
    *(int4*)&off[base] = o;
    *(int4*)&pos[base] = o;
  } else {
    if (base + 0 < n) { off[base + 0] = o.x; pos[base + 0] = o.x; }
    if (base + 1 < n) { off[base + 1] = o.y; pos[base + 1] = o.y; }
    if (base + 2 < n) { off[base + 2] = o.z; pos[base + 2] = o.z; }
  }
}

__global__ __launch_bounds__(256) void k_fill(const int* __restrict__ src,
    const int* __restrict__ dst, const float* __restrict__ w,
    const float* __restrict__ dinv, int* __restrict__ pos,
    int* __restrict__ csrc, float* __restrict__ cnorm, int E) {
  int e = blockIdx.x * 256 + threadIdx.x;
  if (e < E) {
    int s = src[e], d = dst[e];
    int p = atomicAdd(&pos[d], 1);
    csrc[p] = s;
    cnorm[p] = dinv[s] * w[e] * dinv[d];
  }
}

// ---------------- fp32 GEMM, K=128, NOUT in {128, 64} ----------------
// 64-row tile staged in LDS (padded stride); each thread: 8 cols x RPT rows.
// MODE 0: plain load. MODE 1: bn(scsh)+relu on load, side-write to Rout.
// MODE 2: bn(scsh)+relu+residual(Rres) on load.

#define TMG 64
template <int NOUT, int MODE>
__global__ __launch_bounds__(256) void k_gemm(const float* __restrict__ X,
    const float* __restrict__ W, float* __restrict__ Y, int n,
    const float* __restrict__ scsh, const float4* __restrict__ Rres,
    float4* __restrict__ Rout) {
  constexpr int NCT = NOUT / 8;        // threads covering cols (8 cols each)
  constexpr int NRG = 256 / NCT;       // row groups
  constexpr int RPT = TMG / NRG;       // rows per thread
  constexpr int LDSTR = 132;           // padded row stride (floats), 16B-aligned
  __shared__ float xs[TMG * LDSTR];
  const int t = threadIdx.x;
  const int ct = t % NCT;
  const int rg = t / NCT;
  const int c = ct * 8;
  const int row0 = blockIdx.x * TMG;
  for (int i = t; i < TMG * 32; i += 256) {
    int r = i >> 5, q = i & 31;
    bool valid = (row0 + r) < n;
    float4 v = valid ? ((const float4*)X)[(size_t)(row0 + r) * 32 + q]
                     : make_float4(0.f, 0.f, 0.f, 0.f);
    if (MODE >= 1) {
      int c0 = q * 4;
      v.x = fmaxf(v.x * scsh[c0 + 0] + scsh[128 + c0 + 0], 0.f);
      v.y = fmaxf(v.y * scsh[c0 + 1] + scsh[128 + c0 + 1], 0.f);
      v.z = fmaxf(v.z * scsh[c0 + 2] + scsh[128 + c0 + 2], 0.f);
      v.w = fmaxf(v.w * scsh[c0 + 3] + scsh[128 + c0 + 3], 0.f);
      if (MODE == 2 && valid) {
        float4 rr = Rres[(size_t)(row0 + r) * 32 + q];
        v.x += rr.x; v.y += rr.y; v.z += rr.z; v.w += rr.w;
      }
      if (MODE == 1 && valid) Rout[(size_t)(row0 + r) * 32 + q] = v;
    }
    *(float4*)&xs[r * LDSTR + q * 4] = v;
  }
  __syncthreads();
  float acc[RPT][8];
#pragma unroll
  for (int i = 0; i < RPT; ++i)
#pragma unroll
    for (int j = 0; j < 8; ++j) acc[i][j] = 0.f;

#pragma unroll 4
  for (int k = 0; k < 128; k += 4) {
    float4 wa[4], wb[4];
#pragma unroll
    for (int kk = 0; kk < 4; ++kk) {
      wa[kk] = *(const float4*)&W[(size_t)(k + kk) * NOUT + c];
      wb[kk] = *(const float4*)&W[(size_t)(k + kk) * NOUT + c + 4];
    }
#pragma unroll
    for (int ri = 0; ri < RPT; ++ri) {
      const int rl = rg * RPT + ri;
      float4 xv = *(const float4*)&xs[rl * LDSTR + k];
      acc[ri][0] = fmaf(xv.x, wa[0].x, acc[ri][0]);
      acc[ri][1] = fmaf(xv.x, wa[0].y, acc[ri][1]);
      acc[ri][2] = fmaf(xv.x, wa[0].z, acc[ri][2]);
      acc[ri][3] = fmaf(xv.x, wa[0].w, acc[ri][3]);
      acc[ri][4] = fmaf(xv.x, wb[0].x, acc[ri][4]);
      acc[ri][5] = fmaf(xv.x, wb[0].y, acc[ri][5]);
      acc[ri][6] = fmaf(xv.x, wb[0].z, acc[ri][6]);
      acc[ri][7] = fmaf(xv.x, wb[0].w, acc[ri][7]);
      acc[ri][0] = fmaf(xv.y, wa[1].x, acc[ri][0]);
      acc[ri][1] = fmaf(xv.y, wa[1].y, acc[ri][1]);
      acc[ri][2] = fmaf(xv.y, wa[1].z, acc[ri][2]);
      acc[ri][3] = fmaf(xv.y, wa[1].w, acc[ri][3]);
      acc[ri][4] = fmaf(xv.y, wb[1].x, acc[ri][4]);
      acc[ri][5] = fmaf(xv.y, wb[1].y, acc[ri][5]);
      acc[ri][6] = fmaf(xv.y, wb[1].z, acc[ri][6]);
      acc[ri][7] = fmaf(xv.y, wb[1].w, acc[ri][7]);
      acc[ri][0] = fmaf(xv.z, wa[2].x, acc[ri][0]);
      acc[ri][1] = fmaf(xv.z, wa[2].y, acc[ri][1]);
      acc[ri][2] = fmaf(xv.z, wa[2].z, acc[ri][2]);
      acc[ri][3] = fmaf(xv.z, wa[2].w, acc[ri][3]);
      acc[ri][4] = fmaf(xv.z, wb[2].x, acc[ri][4]);
      acc[ri][5] = fmaf(xv.z, wb[2].y, acc[ri][5]);
      acc[ri][6] = fmaf(xv.z, wb[2].z, acc[ri][6]);
      acc[ri][7] = fmaf(xv.z, wb[2].w, acc[ri][7]);
      acc[ri][0] = fmaf(xv.w, wa[3].x, acc[ri][0]);
      acc[ri][1] = fmaf(xv.w, wa[3].y, acc[ri][1]);
      acc[ri][2] = fmaf(xv.w, wa[3].z, acc[ri][2]);
      acc[ri][3] = fmaf(xv.w, wa[3].w, acc[ri][3]);
      acc[ri][4] = fmaf(xv.w, wb[3].x, acc[ri][4]);
      acc[ri][5] = fmaf(xv.w, wb[3].y, acc[ri][5]);
      acc[ri][6] = fmaf(xv.w, wb[3].z, acc[ri][6]);
      acc[ri][7] = fmaf(xv.w, wb[3].w, acc[ri][7]);
    }
  }
#pragma unroll
  for (int ri = 0; ri < RPT; ++ri) {
    int r = row0 + rg * RPT + ri;
    if (r < n) {
      *(float4*)&Y[(size_t)r * NOUT + c] =
          make_float4(acc[ri][0], acc[ri][1], acc[ri][2], acc[ri][3]);
      *(float4*)&Y[(size_t)r * NOUT + c + 4] =
          make_float4(acc[ri][4], acc[ri][5], acc[ri][6], acc[ri][7]);
    }
  }
}

// ---------------- CSR propagation: out[d] = sum norm*T[src] + self + bias ----
// float4 lanes: F/4 threads per node.
template <int F>
__global__ __launch_bounds__(256) void k_prop4(const float* __restrict__ T,
    const float* __restrict__ dinv, const int* __restrict__ off,
    const int* __restrict__ csrc, const float* __restrict__ cnorm,
    const float* __restrict__ bias, float* __restrict__ out, int n) {
  constexpr int TPN = F / 4;
  constexpr int NPB = 256 / TPN;
  int node = blockIdx.x * NPB + threadIdx.x / TPN;
  int f4 = threadIdx.x % TPN;
  if (node >= n) return;
  const float4* T4 = (const float4*)T;
  float di = dinv[node];
  float sw = di * di;
  float4 x = T4[(size_t)node * TPN + f4];
  float4 acc = make_float4(sw * x.x, sw * x.y, sw * x.z, sw * x.w);
  int e = off[node], eend = off[node + 1];
  for (; e + 1 < eend; e += 2) {
    int s0 = csrc[e], s1 = csrc[e + 1];
    float n0 = cnorm[e], n1 = cnorm[e + 1];
    float4 v0 = T4[(size_t)s0 * TPN + f4];
    float4 v1 = T4[(size_t)s1 * TPN + f4];
    acc.x = fmaf(n0, v0.x, acc.x); acc.y = fmaf(n0, v0.y, acc.y);
    acc.z = fmaf(n0, v0.z, acc.z); acc.w = fmaf(n0, v0.w, acc.w);
    acc.x = fmaf(n1, v1.x, acc.x); acc.y = fmaf(n1, v1.y, acc.y);
    acc.z = fmaf(n1, v1.z, acc.z); acc.w = fmaf(n1, v1.w, acc.w);
  }
  if (e < eend) {
    float nw = cnorm[e];
    float4 v = T4[(size_t)csrc[e] * TPN + f4];
    acc.x = fmaf(nw, v.x, acc.x); acc.y = fmaf(nw, v.y, acc.y);
    acc.z = fmaf(nw, v.z, acc.z); acc.w = fmaf(nw, v.w, acc.w);
  }
  float4 b = *(const float4*)&bias[f4 * 4];
  acc.x += b.x; acc.y += b.y; acc.z += b.z; acc.w += b.w;
  ((float4*)out)[(size_t)node * TPN + f4] = acc;
}

// ---------------- BatchNorm stats ----------------

__global__ __launch_bounds__(128) void k_stats(const float* __restrict__ X,
    float* __restrict__ stats, int n) {
  int col = threadIdx.x;
  float s = 0.f, s2 = 0.f;
  for (int r = blockIdx.x; r < n; r += gridDim.x) {
    float v = X[(size_t)r * 128 + col];
    s += v; s2 += v * v;
  }
  atomicAdd(&stats[col], s);
  atomicAdd(&stats[128 + col], s2);
}

__global__ __launch_bounds__(128) void k_bnfin(const float* __restrict__ stats,
    const float* __restrict__ g, const float* __restrict__ be,
    float* __restrict__ scsh, int n) {
  int c = threadIdx.x;
  float m = stats[c] / (float)n;
  float var = stats[128 + c] / (float)n - m * m;
  var = fmaxf(var, 0.f);
  float sc = g[c] * rsqrtf(var + 1e-5f);
  scsh[c] = sc;
  scsh[128 + c] = be[c] - m * sc;
}

// ---------------- head weight concat + final reparam ----------------

__global__ __launch_bounds__(256) void k_concat(const float* __restrict__ Wm,
    const float* __restrict__ bm, const float* __restrict__ Ws,
    const float* __restrict__ bs, float* __restrict__ wcat,
    float* __restrict__ bcat) {
  int t = blockIdx.x * 256 + threadIdx.x;
  if (t < 128 * 64) {
    int k = t / 64, c = t % 64;
    wcat[t] = (c < 32) ? Wm[k * 32 + c] : Ws[k * 32 + (c - 32)];
  } else if (t < 128 * 64 + 64) {
    int c = t - 128 * 64;
    bcat[c] = (c < 32) ? bm[c] : bs[c - 32];
  }
}

__global__ __launch_bounds__(256) void k_final(const float* __restrict__ agg,
    const float* __restrict__ eps, float* __restrict__ out, int n) {
  int i = blockIdx.x * 256 + threadIdx.x;
  int M = n * 32;
  if (i >= M) return;
  int node = i >> 5, j = i & 31;
  float qm = agg[(size_t)node * 64 + j];
  float qs = agg[(size_t)node * 64 + 32 + j];
  float sp = fmaxf(qs, 0.f) + log1pf(expf(-fabsf(qs)));
  float stdv = sp + 1e-6f;
  out[i] = qm + stdv * eps[i];
  out[M + i] = qm;
  out[2 * M + i] = qs;
}

// ---------------- launch ----------------

extern "C" void kernel_launch(void* const* d_in, const int* in_sizes, int n_in,
                              void* d_out, int out_size, void* d_ws, size_t ws_size,
                              hipStream_t stream) {
  const float* x  = (const float*)d_in[0];
  const int*   ei = (const int*)d_in[1];
  const float* ew = (const float*)d_in[2];
  const float* W0 = (const float*)d_in[3];
  const float* b0 = (const float*)d_in[4];
  const float* W1 = (const float*)d_in[5];
  const float* b1 = (const float*)d_in[6];
  const float* g0 = (const float*)d_in[7];
  const float* be0 = (const float*)d_in[8];
  const float* g1 = (const float*)d_in[9];
  const float* be1 = (const float*)d_in[10];
  const float* Wm = (const float*)d_in[11];
  const float* bm = (const float*)d_in[12];
  const float* Ws = (const float*)d_in[13];
  const float* bs = (const float*)d_in[14];
  const float* eps = (const float*)d_in[15];
  float* out = (float*)d_out;

  const int n = in_sizes[0] / HID;
  const int E = in_sizes[1] / 2;
  const int* esrc = ei;
  const int* edst = ei + E;

  // workspace layout (256B aligned)
  char* base = (char*)d_ws;
  size_t cur = 0;
  auto alloc = [&](size_t bytes) {
    size_t o = cur;
    cur = (cur + bytes + 255) & ~(size_t)255;
    return (void*)(base + o);
  };
  float* deg   = (float*)alloc((size_t)n * 4);        // becomes dinv
  int*   cnt   = (int*)alloc((size_t)n * 4);
  int*   coff  = (int*)alloc((size_t)(n + 1) * 4);
  int*   cpos  = (int*)alloc((size_t)n * 4);
  int*   csrc  = (int*)alloc((size_t)E * 4);
  float* cnorm = (float*)alloc((size_t)E * 4);
  int*   bsum  = (int*)alloc(64 * 4);
  int*   boff  = (int*)alloc(64 * 4);
  float* stats = (float*)alloc(256 * 4);
  float* scsh0 = (float*)alloc(256 * 4);
  float* scsh1 = (float*)alloc(256 * 4);
  float* wcat  = (float*)alloc(128 * 64 * 4);
  float* bcat  = (float*)alloc(64 * 4);
  float* bufA  = (float*)alloc((size_t)n * 128 * 4);
  float* bufB  = (float*)alloc((size_t)n * 128 * 4);
  float* bufC  = (float*)alloc((size_t)n * 128 * 4);
  (void)ws_size;

  const int nb = (n + 255) / 256;
  const int eb = (E + 255) / 256;
  const int gemmb = (n + TMG - 1) / TMG;
  const int scb = (n + SCH - 1) / SCH;  // <= 64 for n <= 65536
  const int mlat = n * 32;              // latent elements
  const int mlatb = (mlat + 255) / 256;

  // --- norm + CSR ---
  hipMemsetAsync(cnt, 0, (size_t)n * 4, stream);
  k_deg_init<<<nb, 256, 0, stream>>>(deg, n);
  k_deg_edges<<<eb, 256, 0, stream>>>(edst, ew, deg, cnt, E);
  k_dinv<<<nb, 256, 0, stream>>>(deg, n);
  k_scan_part<<<scb, 256, 0, stream>>>(cnt, bsum, n);
  k_scan_mid<<<1, 64, 0, stream>>>(bsum, boff, coff, scb, n);
  k_scan_out<<<scb, 256, 0, stream>>>(cnt, boff, coff, cpos, n);
  k_fill<<<eb, 256, 0, stream>>>(esrc, edst, ew, deg, cpos, csrc, cnorm, E);
  k_concat<<<(128 * 64 + 64 + 255) / 256, 256, 0, stream>>>(Wm, bm, Ws, bs, wcat, bcat);

  // --- layer 0: conv0 = prop(x @ W0) ---
  k_gemm<128, 0><<<gemmb, 256, 0, stream>>>(x, W0, bufA, n, nullptr, nullptr, nullptr);
  k_prop4<128><<<(n + 7) / 8, 256, 0, stream>>>(bufA, deg, coff, csrc, cnorm, b0, bufB, n);
  hipMemsetAsync(stats, 0, 256 * 4, stream);
  k_stats<<<512, 128, 0, stream>>>(bufB, stats, n);
  k_bnfin<<<1, 128, 0, stream>>>(stats, g0, be0, scsh0, n);

  // --- layer 1: gemm applies bn0+relu on load, saves residual h0 -> bufC ---
  k_gemm<128, 1><<<gemmb, 256, 0, stream>>>(bufB, W1, bufA, n, scsh0, nullptr,
                                            (float4*)bufC);
  k_prop4<128><<<(n + 7) / 8, 256, 0, stream>>>(bufA, deg, coff, csrc, cnorm, b1, bufB, n);
  hipMemsetAsync(stats, 0, 256 * 4, stream);
  k_stats<<<512, 128, 0, stream>>>(bufB, stats, n);
  k_bnfin<<<1, 128, 0, stream>>>(stats, g1, be1, scsh1, n);

  // --- heads: gemm applies bn1+relu+residual on load; fused mean||logstd ---
  k_gemm<64, 2><<<gemmb, 256, 0, stream>>>(bufB, wcat, bufA, n, scsh1,
                                           (const float4*)bufC, nullptr);
  k_prop4<64><<<(n + 15) / 16, 256, 0, stream>>>(bufA, deg, coff, csrc, cnorm, bcat, bufB, n);

  // --- reparameterization + output ---
  k_final<<<mlatb, 256, 0, stream>>>(bufB, eps, out, n);
}

// Round 4
// 401.814 us; speedup vs baseline: 4.5532x; 1.2749x over previous
//
#include <hip/hip_runtime.h>
#include <hip/hip_bf16.h>
#include <math.h>

// GraphEncoderStack: 2x (GCNConv -> BN -> ReLU) + residual + 2 GCN heads + reparam
// N=50000 nodes, E=800000 edges, IN=HIDDEN=128, LATENT=32.
// fp32 math; GEMM->prop intermediates in bf16 (threshold 0.12, we were at 0.016).

#define HID 128
#define LAT 32

// ---------------- degree+count in one packed 64-bit atomic ----------------
// packed[d] += (1<<48) | (w * 2^24). Count in hi16, fixed-point weight sum in
// low 48 (max sum 2^24, exact integer adds -> order-independent/deterministic).

__global__ __launch_bounds__(256) void k_deg_edges(const int* __restrict__ dst,
    const float* __restrict__ w, unsigned long long* __restrict__ packed, int E) {
  int e = blockIdx.x * 256 + threadIdx.x;
  if (e < E) {
    int d = dst[e];
    unsigned long long v =
        (1ULL << 48) | (unsigned long long)(w[e] * 16777216.0f);
    atomicAdd(&packed[d], v);
  }
}

__global__ __launch_bounds__(256) void k_dinv(
    const unsigned long long* __restrict__ packed, float* __restrict__ dinv,
    int* __restrict__ cnt, int n) {
  int i = blockIdx.x * 256 + threadIdx.x;
  if (i < n) {
    unsigned long long p = packed[i];
    cnt[i] = (int)(p >> 48);
    float d = (float)(p & 0xFFFFFFFFFFFFULL) * (1.0f / 16777216.0f) + 1.0f;
    dinv[i] = rsqrtf(d);  // d >= 1 (self loop)
  }
}

// ---------------- hierarchical exclusive scan (n <= 65536) ----------------
#define SCH 1024

__global__ __launch_bounds__(256) void k_scan_part(const int* __restrict__ cnt,
    int* __restrict__ bsum, int n) {
  int base = blockIdx.x * SCH + threadIdx.x * 4;
  int4 v = make_int4(0, 0, 0, 0);
  if (base + 3 < n) v = *(const int4*)&cnt[base];
  else {
    if (base + 0 < n) v.x = cnt[base + 0];
    if (base + 1 < n) v.y = cnt[base + 1];
    if (base + 2 < n) v.z = cnt[base + 2];
  }
  int s = v.x + v.y + v.z + v.w;
#pragma unroll
  for (int off = 32; off; off >>= 1) s += __shfl_down(s, off);
  __shared__ int ws[4];
  if ((threadIdx.x & 63) == 0) ws[threadIdx.x >> 6] = s;
  __syncthreads();
  if (threadIdx.x == 0) bsum[blockIdx.x] = ws[0] + ws[1] + ws[2] + ws[3];
}

__global__ __launch_bounds__(64) void k_scan_mid(const int* __restrict__ bsum,
    int* __restrict__ boff, int* __restrict__ off, int nb, int n) {
  int t = threadIdx.x;
  int val = (t < nb) ? bsum[t] : 0;
  int inc = val;
#pragma unroll
  for (int d = 1; d < 64; d <<= 1) {
    int u = __shfl_up(inc, d);
    if (t >= d) inc += u;
  }
  if (t < nb) boff[t] = inc - val;
  if (t == nb - 1) off[n] = inc;  // grand total = E + n
}

__global__ __launch_bounds__(256) void k_scan_out(const int* __restrict__ cnt,
    const int* __restrict__ boff, int* __restrict__ off, int* __restrict__ pos,
    int n) {
  int base = blockIdx.x * SCH + threadIdx.x * 4;
  int4 v = make_int4(0, 0, 0, 0);
  if (base + 3 < n) v = *(const int4*)&cnt[base];
  else {
    if (base + 0 < n) v.x = cnt[base + 0];
    if (base + 1 < n) v.y = cnt[base + 1];
    if (base + 2 < n) v.z = cnt[base + 2];
  }
  int s = v.x + v.y + v.z + v.w;
  int lane = threadIdx.x & 63, wv = threadIdx.x >> 6;
  int inc = s;
#pragma unroll
  for (int d = 1; d < 64; d <<= 1) {
    int u = __shfl_up(inc, d);
    if (lane >= d) inc += u;
  }
  __shared__ int wsum[4];
  if (lane == 63) wsum[wv] = inc;
  __syncthreads();
  int wbase = 0;
  for (int i = 0; i < wv; ++i) wbase += wsum[i];
  int ex = boff[blockIdx.x] + wbase + inc - s;
  int4 o = make_int4(ex, ex + v.x, ex + v.x + v.y, ex + v.x + v.y + v.z);
  if (base + 3 < n) {
    *(int4*)&off[base] = o;
    *(int4*)&pos[base] = o;
  } else {
    if (base + 0 < n) { off[base + 0] = o.x; pos[base + 0] = o.x; }
    if (base + 1 < n) { off[base + 1] = o.y; pos[base + 1] = o.y; }
    if (base + 2 < n) { off[base + 2] = o.z; pos[base + 2] = o.z; }
  }
}

// CSR entry packed as int2 {src, norm-bits}: one 8B store / 8B load.
__global__ __launch_bounds__(256) void k_fill(const int* __restrict__ src,
    const int* __restrict__ dst, const float* __restrict__ w,
    const float* __restrict__ dinv, int* __restrict__ pos,
    int2* __restrict__ erec, int E) {
  int e = blockIdx.x * 256 + threadIdx.x;
  if (e < E) {
    int s = src[e], d = dst[e];
    int p = atomicAdd(&pos[d], 1);
    erec[p] = make_int2(s, __float_as_int(dinv[s] * w[e] * dinv[d]));
  }
}

// ---------------- fp32 GEMM -> bf16 output, K=128, NOUT in {128, 64} -------
// 64-row LDS tile; thread: 8 cols x RPT rows. MODE 0 plain; MODE 1 bn+relu on
// load + residual side-write; MODE 2 bn+relu+residual add on load.

__device__ __forceinline__ unsigned bf2(float a, float b) {
  unsigned ua = __float_as_uint(a);
  ua += 0x7FFFu + ((ua >> 16) & 1u);
  unsigned ub = __float_as_uint(b);
  ub += 0x7FFFu + ((ub >> 16) & 1u);
  return (ua >> 16) | (ub & 0xFFFF0000u);
}

#define TMG 64
template <int NOUT, int MODE>
__global__ __launch_bounds__(256) void k_gemm(const float* __restrict__ X,
    const float* __restrict__ W, unsigned short* __restrict__ Y, int n,
    const float* __restrict__ scsh, const float4* __restrict__ Rres,
    float4* __restrict__ Rout) {
  constexpr int NCT = NOUT / 8;
  constexpr int NRG = 256 / NCT;
  constexpr int RPT = TMG / NRG;
  constexpr int LDSTR = 132;
  __shared__ float xs[TMG * LDSTR];
  const int t = threadIdx.x;
  const int ct = t % NCT;
  const int rg = t / NCT;
  const int c = ct * 8;
  const int row0 = blockIdx.x * TMG;
  for (int i = t; i < TMG * 32; i += 256) {
    int r = i >> 5, q = i & 31;
    bool valid = (row0 + r) < n;
    float4 v = valid ? ((const float4*)X)[(size_t)(row0 + r) * 32 + q]
                     : make_float4(0.f, 0.f, 0.f, 0.f);
    if (MODE >= 1) {
      int c0 = q * 4;
      v.x = fmaxf(v.x * scsh[c0 + 0] + scsh[128 + c0 + 0], 0.f);
      v.y = fmaxf(v.y * scsh[c0 + 1] + scsh[128 + c0 + 1], 0.f);
      v.z = fmaxf(v.z * scsh[c0 + 2] + scsh[128 + c0 + 2], 0.f);
      v.w = fmaxf(v.w * scsh[c0 + 3] + scsh[128 + c0 + 3], 0.f);
      if (MODE == 2 && valid) {
        float4 rr = Rres[(size_t)(row0 + r) * 32 + q];
        v.x += rr.x; v.y += rr.y; v.z += rr.z; v.w += rr.w;
      }
      if (MODE == 1 && valid) Rout[(size_t)(row0 + r) * 32 + q] = v;
    }
    *(float4*)&xs[r * LDSTR + q * 4] = v;
  }
  __syncthreads();
  float acc[RPT][8];
#pragma unroll
  for (int i = 0; i < RPT; ++i)
#pragma unroll
    for (int j = 0; j < 8; ++j) acc[i][j] = 0.f;

#pragma unroll 4
  for (int k = 0; k < 128; k += 4) {
    float4 wa[4], wb[4];
#pragma unroll
    for (int kk = 0; kk < 4; ++kk) {
      wa[kk] = *(const float4*)&W[(size_t)(k + kk) * NOUT + c];
      wb[kk] = *(const float4*)&W[(size_t)(k + kk) * NOUT + c + 4];
    }
#pragma unroll
    for (int ri = 0; ri < RPT; ++ri) {
      const int rl = rg * RPT + ri;
      float4 xv = *(const float4*)&xs[rl * LDSTR + k];
      acc[ri][0] = fmaf(xv.x, wa[0].x, acc[ri][0]);
      acc[ri][1] = fmaf(xv.x, wa[0].y, acc[ri][1]);
      acc[ri][2] = fmaf(xv.x, wa[0].z, acc[ri][2]);
      acc[ri][3] = fmaf(xv.x, wa[0].w, acc[ri][3]);
      acc[ri][4] = fmaf(xv.x, wb[0].x, acc[ri][4]);
      acc[ri][5] = fmaf(xv.x, wb[0].y, acc[ri][5]);
      acc[ri][6] = fmaf(xv.x, wb[0].z, acc[ri][6]);
      acc[ri][7] = fmaf(xv.x, wb[0].w, acc[ri][7]);
      acc[ri][0] = fmaf(xv.y, wa[1].x, acc[ri][0]);
      acc[ri][1] = fmaf(xv.y, wa[1].y, acc[ri][1]);
      acc[ri][2] = fmaf(xv.y, wa[1].z, acc[ri][2]);
      acc[ri][3] = fmaf(xv.y, wa[1].w, acc[ri][3]);
      acc[ri][4] = fmaf(xv.y, wb[1].x, acc[ri][4]);
      acc[ri][5] = fmaf(xv.y, wb[1].y, acc[ri][5]);
      acc[ri][6] = fmaf(xv.y, wb[1].z, acc[ri][6]);
      acc[ri][7] = fmaf(xv.y, wb[1].w, acc[ri][7]);
      acc[ri][0] = fmaf(xv.z, wa[2].x, acc[ri][0]);
      acc[ri][1] = fmaf(xv.z, wa[2].y, acc[ri][1]);
      acc[ri][2] = fmaf(xv.z, wa[2].z, acc[ri][2]);
      acc[ri][3] = fmaf(xv.z, wa[2].w, acc[ri][3]);
      acc[ri][4] = fmaf(xv.z, wb[2].x, acc[ri][4]);
      acc[ri][5] = fmaf(xv.z, wb[2].y, acc[ri][5]);
      acc[ri][6] = fmaf(xv.z, wb[2].z, acc[ri][6]);
      acc[ri][7] = fmaf(xv.z, wb[2].w, acc[ri][7]);
      acc[ri][0] = fmaf(xv.w, wa[3].x, acc[ri][0]);
      acc[ri][1] = fmaf(xv.w, wa[3].y, acc[ri][1]);
      acc[ri][2] = fmaf(xv.w, wa[3].z, acc[ri][2]);
      acc[ri][3] = fmaf(xv.w, wa[3].w, acc[ri][3]);
      acc[ri][4] = fmaf(xv.w, wb[3].x, acc[ri][4]);
      acc[ri][5] = fmaf(xv.w, wb[3].y, acc[ri][5]);
      acc[ri][6] = fmaf(xv.w, wb[3].z, acc[ri][6]);
      acc[ri][7] = fmaf(xv.w, wb[3].w, acc[ri][7]);
    }
  }
#pragma unroll
  for (int ri = 0; ri < RPT; ++ri) {
    int r = row0 + rg * RPT + ri;
    if (r < n) {
      uint4 pk;
      pk.x = bf2(acc[ri][0], acc[ri][1]);
      pk.y = bf2(acc[ri][2], acc[ri][3]);
      pk.z = bf2(acc[ri][4], acc[ri][5]);
      pk.w = bf2(acc[ri][6], acc[ri][7]);
      *(uint4*)&Y[(size_t)r * NOUT + c] = pk;
    }
  }
}

// ------------- CSR propagation over bf16 rows: out fp32 ----------------
// T rows = F bf16 (F/8 uint4). TPN=F/8 threads per node, 8 feats each.
template <int F>
__global__ __launch_bounds__(256) void k_propb(const uint4* __restrict__ T,
    const float* __restrict__ dinv, const int* __restrict__ off,
    const int2* __restrict__ erec, const float* __restrict__ bias,
    float* __restrict__ out, int n) {
  constexpr int TPN = F / 8;
  constexpr int NPB = 256 / TPN;
  int node = blockIdx.x * NPB + threadIdx.x / TPN;
  int f8 = threadIdx.x % TPN;
  if (node >= n) return;
  float di = dinv[node];
  float sw = di * di;
  float acc[8];
  {
    uint4 v = T[(size_t)node * TPN + f8];
    acc[0] = sw * __uint_as_float(v.x << 16);
    acc[1] = sw * __uint_as_float(v.x & 0xFFFF0000u);
    acc[2] = sw * __uint_as_float(v.y << 16);
    acc[3] = sw * __uint_as_float(v.y & 0xFFFF0000u);
    acc[4] = sw * __uint_as_float(v.z << 16);
    acc[5] = sw * __uint_as_float(v.z & 0xFFFF0000u);
    acc[6] = sw * __uint_as_float(v.w << 16);
    acc[7] = sw * __uint_as_float(v.w & 0xFFFF0000u);
  }
  int e = off[node], eend = off[node + 1];
  for (; e + 1 < eend; e += 2) {
    int2 r0 = erec[e], r1 = erec[e + 1];
    uint4 v0 = T[(size_t)r0.x * TPN + f8];
    uint4 v1 = T[(size_t)r1.x * TPN + f8];
    float n0 = __int_as_float(r0.y), n1 = __int_as_float(r1.y);
    acc[0] = fmaf(n0, __uint_as_float(v0.x << 16), acc[0]);
    acc[1] = fmaf(n0, __uint_as_float(v0.x & 0xFFFF0000u), acc[1]);
    acc[2] = fmaf(n0, __uint_as_float(v0.y << 16), acc[2]);
    acc[3] = fmaf(n0, __uint_as_float(v0.y & 0xFFFF0000u), acc[3]);
    acc[4] = fmaf(n0, __uint_as_float(v0.z << 16), acc[4]);
    acc[5] = fmaf(n0, __uint_as_float(v0.z & 0xFFFF0000u), acc[5]);
    acc[6] = fmaf(n0, __uint_as_float(v0.w << 16), acc[6]);
    acc[7] = fmaf(n0, __uint_as_float(v0.w & 0xFFFF0000u), acc[7]);
    acc[0] = fmaf(n1, __uint_as_float(v1.x << 16), acc[0]);
    acc[1] = fmaf(n1, __uint_as_float(v1.x & 0xFFFF0000u), acc[1]);
    acc[2] = fmaf(n1, __uint_as_float(v1.y << 16), acc[2]);
    acc[3] = fmaf(n1, __uint_as_float(v1.y & 0xFFFF0000u), acc[3]);
    acc[4] = fmaf(n1, __uint_as_float(v1.z << 16), acc[4]);
    acc[5] = fmaf(n1, __uint_as_float(v1.z & 0xFFFF0000u), acc[5]);
    acc[6] = fmaf(n1, __uint_as_float(v1.w << 16), acc[6]);
    acc[7] = fmaf(n1, __uint_as_float(v1.w & 0xFFFF0000u), acc[7]);
  }
  if (e < eend) {
    int2 r0 = erec[e];
    uint4 v0 = T[(size_t)r0.x * TPN + f8];
    float n0 = __int_as_float(r0.y);
    acc[0] = fmaf(n0, __uint_as_float(v0.x << 16), acc[0]);
    acc[1] = fmaf(n0, __uint_as_float(v0.x & 0xFFFF0000u), acc[1]);
    acc[2] = fmaf(n0, __uint_as_float(v0.y << 16), acc[2]);
    acc[3] = fmaf(n0, __uint_as_float(v0.y & 0xFFFF0000u), acc[3]);
    acc[4] = fmaf(n0, __uint_as_float(v0.z << 16), acc[4]);
    acc[5] = fmaf(n0, __uint_as_float(v0.z & 0xFFFF0000u), acc[5]);
    acc[6] = fmaf(n0, __uint_as_float(v0.w << 16), acc[6]);
    acc[7] = fmaf(n0, __uint_as_float(v0.w & 0xFFFF0000u), acc[7]);
  }
  float4 b0 = *(const float4*)&bias[f8 * 8];
  float4 b1 = *(const float4*)&bias[f8 * 8 + 4];
  float* op = &out[(size_t)node * F + f8 * 8];
  *(float4*)op = make_float4(acc[0] + b0.x, acc[1] + b0.y, acc[2] + b0.z,
                             acc[3] + b0.w);
  *(float4*)(op + 4) = make_float4(acc[4] + b1.x, acc[5] + b1.y,
                                   acc[6] + b1.z, acc[7] + b1.w);
}

// ---------------- BatchNorm stats ----------------

__global__ __launch_bounds__(128) void k_stats(const float* __restrict__ X,
    float* __restrict__ stats, int n) {
  int col = threadIdx.x;
  float s = 0.f, s2 = 0.f;
  for (int r = blockIdx.x; r < n; r += gridDim.x) {
    float v = X[(size_t)r * 128 + col];
    s += v; s2 += v * v;
  }
  atomicAdd(&stats[col], s);
  atomicAdd(&stats[128 + col], s2);
}

__global__ __launch_bounds__(128) void k_bnfin(const float* __restrict__ stats,
    const float* __restrict__ g, const float* __restrict__ be,
    float* __restrict__ scsh, int n) {
  int c = threadIdx.x;
  float m = stats[c] / (float)n;
  float var = stats[128 + c] / (float)n - m * m;
  var = fmaxf(var, 0.f);
  float sc = g[c] * rsqrtf(var + 1e-5f);
  scsh[c] = sc;
  scsh[128 + c] = be[c] - m * sc;
}

// ---------------- head weight concat + final reparam ----------------

__global__ __launch_bounds__(256) void k_concat(const float* __restrict__ Wm,
    const float* __restrict__ bm, const float* __restrict__ Ws,
    const float* __restrict__ bs, float* __restrict__ wcat,
    float* __restrict__ bcat) {
  int t = blockIdx.x * 256 + threadIdx.x;
  if (t < 128 * 64) {
    int k = t / 64, c = t % 64;
    wcat[t] = (c < 32) ? Wm[k * 32 + c] : Ws[k * 32 + (c - 32)];
  } else if (t < 128 * 64 + 64) {
    int c = t - 128 * 64;
    bcat[c] = (c < 32) ? bm[c] : bs[c - 32];
  }
}

__global__ __launch_bounds__(256) void k_final(const float* __restrict__ agg,
    const float* __restrict__ eps, float* __restrict__ out, int n) {
  int i = blockIdx.x * 256 + threadIdx.x;
  int M = n * 32;
  if (i >= M) return;
  int node = i >> 5, j = i & 31;
  float qm = agg[(size_t)node * 64 + j];
  float qs = agg[(size_t)node * 64 + 32 + j];
  float sp = fmaxf(qs, 0.f) + log1pf(expf(-fabsf(qs)));
  float stdv = sp + 1e-6f;
  out[i] = qm + stdv * eps[i];
  out[M + i] = qm;
  out[2 * M + i] = qs;
}

// ---------------- launch ----------------

extern "C" void kernel_launch(void* const* d_in, const int* in_sizes, int n_in,
                              void* d_out, int out_size, void* d_ws, size_t ws_size,
                              hipStream_t stream) {
  const float* x  = (const float*)d_in[0];
  const int*   ei = (const int*)d_in[1];
  const float* ew = (const float*)d_in[2];
  const float* W0 = (const float*)d_in[3];
  const float* b0 = (const float*)d_in[4];
  const float* W1 = (const float*)d_in[5];
  const float* b1 = (const float*)d_in[6];
  const float* g0 = (const float*)d_in[7];
  const float* be0 = (const float*)d_in[8];
  const float* g1 = (const float*)d_in[9];
  const float* be1 = (const float*)d_in[10];
  const float* Wm = (const float*)d_in[11];
  const float* bm = (const float*)d_in[12];
  const float* Ws = (const float*)d_in[13];
  const float* bs = (const float*)d_in[14];
  const float* eps = (const float*)d_in[15];
  float* out = (float*)d_out;

  const int n = in_sizes[0] / HID;
  const int E = in_sizes[1] / 2;
  const int* esrc = ei;
  const int* edst = ei + E;

  char* base = (char*)d_ws;
  size_t cur = 0;
  auto alloc = [&](size_t bytes) {
    size_t o = cur;
    cur = (cur + bytes + 255) & ~(size_t)255;
    return (void*)(base + o);
  };
  unsigned long long* packed = (unsigned long long*)alloc((size_t)n * 8);
  float* dinv  = (float*)alloc((size_t)n * 4);
  int*   cnt   = (int*)alloc((size_t)n * 4);
  int*   coff  = (int*)alloc((size_t)(n + 1) * 4);
  int*   cpos  = (int*)alloc((size_t)n * 4);
  int2*  erec  = (int2*)alloc((size_t)(E + n) * 8);
  int*   bsum  = (int*)alloc(64 * 4);
  int*   boff  = (int*)alloc(64 * 4);
  float* stats = (float*)alloc(256 * 4);
  float* scsh0 = (float*)alloc(256 * 4);
  float* scsh1 = (float*)alloc(256 * 4);
  float* wcat  = (float*)alloc(128 * 64 * 4);
  float* bcat  = (float*)alloc(64 * 4);
  unsigned short* bufA = (unsigned short*)alloc((size_t)n * 128 * 2);  // bf16
  float* bufB  = (float*)alloc((size_t)n * 128 * 4);
  float* bufC  = (float*)alloc((size_t)n * 128 * 4);
  (void)ws_size;

  const int nb = (n + 255) / 256;
  const int eb = (E + 255) / 256;
  const int gemmb = (n + TMG - 1) / TMG;
  const int scb = (n + SCH - 1) / SCH;
  const int mlat = n * 32;
  const int mlatb = (mlat + 255) / 256;

  // --- norm + CSR ---
  hipMemsetAsync(packed, 0, (size_t)n * 8, stream);
  k_deg_edges<<<eb, 256, 0, stream>>>(edst, ew, packed, E);
  k_dinv<<<nb, 256, 0, stream>>>(packed, dinv, cnt, n);
  k_scan_part<<<scb, 256, 0, stream>>>(cnt, bsum, n);
  k_scan_mid<<<1, 64, 0, stream>>>(bsum, boff, coff, scb, n);
  k_scan_out<<<scb, 256, 0, stream>>>(cnt, boff, coff, cpos, n);
  k_fill<<<eb, 256, 0, stream>>>(esrc, edst, ew, dinv, cpos, erec, E);
  k_concat<<<(128 * 64 + 64 + 255) / 256, 256, 0, stream>>>(Wm, bm, Ws, bs, wcat, bcat);

  // --- layer 0 ---
  k_gemm<128, 0><<<gemmb, 256, 0, stream>>>(x, W0, bufA, n, nullptr, nullptr, nullptr);
  k_propb<128><<<(n + 15) / 16, 256, 0, stream>>>((const uint4*)bufA, dinv, coff,
                                                  erec, b0, bufB, n);
  hipMemsetAsync(stats, 0, 256 * 4, stream);
  k_stats<<<512, 128, 0, stream>>>(bufB, stats, n);
  k_bnfin<<<1, 128, 0, stream>>>(stats, g0, be0, scsh0, n);

  // --- layer 1 (bn0+relu fused into gemm load; residual h0 -> bufC) ---
  k_gemm<128, 1><<<gemmb, 256, 0, stream>>>(bufB, W1, bufA, n, scsh0, nullptr,
                                            (float4*)bufC);
  k_propb<128><<<(n + 15) / 16, 256, 0, stream>>>((const uint4*)bufA, dinv, coff,
                                                  erec, b1, bufB, n);
  hipMemsetAsync(stats, 0, 256 * 4, stream);
  k_stats<<<512, 128, 0, stream>>>(bufB, stats, n);
  k_bnfin<<<1, 128, 0, stream>>>(stats, g1, be1, scsh1, n);

  // --- heads (bn1+relu+residual fused into gemm load; mean||logstd) ---
  k_gemm<64, 2><<<gemmb, 256, 0, stream>>>(bufB, wcat, bufA, n, scsh1,
                                           (const float4*)bufC, nullptr);
  k_propb<64><<<(n + 31) / 32, 256, 0, stream>>>((const uint4*)bufA, dinv, coff,
                                                 erec, bcat, bufB, n);

  // --- reparameterization + output ---
  k_final<<<mlatb, 256, 0, stream>>>(bufB, eps, out, n);
}